// Round 2
// baseline (207.449 us; speedup 1.0000x reference)
//
#include <hip/hip_runtime.h>
#include <hip/hip_bf16.h>

// LightGCNConv: out[dst] = sum_e w[e] * x[src_e], N=100000, d=64, E=1250000.
//
// R1: 80M fp32 device atomics -> 275us kernel (atomics at fabric, WRITE=320MB).
// R2: exact CSR; fill 8x write amp 90us + gather 88us -> 295 total.
// R3: per-bucket LDS-accumulate gather, 1563 blocks -> 471us. REVERTED.
// R4: L2-resident CSR build + reg-accumulate gather -> 200 total.
// R5: bf16 x + fixed-cap buckets (no hist/scan) -> 158.7. Harness poison of
//     256MiB d_ws + input restore = ~65us fixed overhead inside dur_us.
// R6: cast+bin fusion, 4-node/wave gather -> 158.4 (neutral).
// R7: fused per-bucket LDS sort+gather, 1024 thr -> 136.4.
// R8: 512-thr sortgather (full residency), shfl scan, ovf folded -> 131.4.
// R9: kill the sort entirely: bin per-NODE with fixed cap 64
//     (deg ~ Poisson(12.5), P(deg>=64) ~ e^-53; ovf path keeps exactness).
//     slot = global atomicAdd(&dcnt[dst]) at bin time gives per-node
//     contiguous segments directly; gather is pure (LDS=0, no barriers):
//     one wave per node, 4 edges/iter across quarter-lanes, shfl_xor
//     cross-quarter reduce, float4 store.
//     Fallback chain: A -> B (R4 exact, proven) -> C (R1).

#define N_NODES   100000
#define N_FEAT    64

// ---------------- Path A ----------------
#define A_DCAP    64                                 // slots per node
#define A_FCHUNK  4096                               // edges per bin block
#define A_OVCAP   65536
#define NBIN      ((1250000 + A_FCHUNK - 1) / A_FCHUNK)   // 306 (E known)
#define NCAST     391   // 391*1024*4 float4 = 1.6016M >= 1.6M

// fused: blocks [0,NBIN) bin edges per-node; blocks [NBIN,NBIN+NCAST) cast x->bf16
__global__ __launch_bounds__(1024) void k_castbin(
    const float* __restrict__ x, ushort* __restrict__ xb,
    const int* __restrict__ ei, const float* __restrict__ w,
    int* __restrict__ dcnt, int2* __restrict__ stg,
    int* __restrict__ ovf, int* __restrict__ ovcnt, int E) {
    int t = threadIdx.x;
    if (blockIdx.x >= NBIN) {
        // ---- cast role ----
        int cb = blockIdx.x - NBIN;
        #pragma unroll
        for (int k = 0; k < 4; ++k) {
            int i4 = cb * 4096 + k * 1024 + t;           // float4 index
            if (i4 < N_NODES * N_FEAT / 4) {
                float4 v = ((const float4*)x)[i4];
                uint4 u = *(uint4*)&v;
                ushort4 r;
                r.x = (ushort)((u.x + 0x7FFFu + ((u.x >> 16) & 1)) >> 16);
                r.y = (ushort)((u.y + 0x7FFFu + ((u.y >> 16) & 1)) >> 16);
                r.z = (ushort)((u.z + 0x7FFFu + ((u.z >> 16) & 1)) >> 16);
                r.w = (ushort)((u.w + 0x7FFFu + ((u.w >> 16) & 1)) >> 16);
                ((ushort4*)xb)[i4] = r;
            }
        }
        return;
    }
    // ---- bin role: per-node slot via global atomic (L2, ~12.5 ops/addr) ----
    int e0 = blockIdx.x * A_FCHUNK;
    #pragma unroll
    for (int k = 0; k < A_FCHUNK / 1024; ++k) {
        int e = e0 + k * 1024 + t;
        if (e < E) {
            int dst = ei[E + e];
            int src = ei[e];
            float wv = w[e];
            int slot = atomicAdd(&dcnt[dst], 1);
            if (slot < A_DCAP) {
                stg[(size_t)dst * A_DCAP + slot] =
                    make_int2(src, __float_as_int(wv));
            } else {
                int oi = atomicAdd(ovcnt, 1);
                if (oi < A_OVCAP) ovf[oi] = e;
            }
        }
    }
}

// pure gather: one wave per node; quarter-lanes split edges 4-way,
// shfl_xor(16/32) reduces quarters; no LDS, no barriers.
__global__ __launch_bounds__(256) void k_ngather(
    const ushort* __restrict__ xb, const int* __restrict__ dcnt,
    const int2* __restrict__ stg, float* __restrict__ out,
    const float* __restrict__ x, const int* __restrict__ ei,
    const float* __restrict__ w, const int* __restrict__ ovf,
    const int* __restrict__ ovcnt, int E) {
    int node = blockIdx.x * 4 + (threadIdx.x >> 6);
    if (node >= N_NODES) return;
    int lane = threadIdx.x & 63;
    int q    = lane >> 4;              // quarter slot: edge phase
    int l    = lane & 15;              // ushort4 feature column
    int cnt = dcnt[node];
    int c = cnt < A_DCAP ? cnt : A_DCAP;
    const int2*    ps  = &stg[(size_t)node * A_DCAP];
    const ushort4* xb4 = (const ushort4*)xb;
    float ax = 0.f, ay = 0.f, az = 0.f, aw = 0.f;
    for (int j = q; j < c; j += 4) {
        int2 p = ps[j];                 // 16 lanes broadcast-read same 8B
        ushort4 u = xb4[(size_t)p.x * 16 + l];
        float wv = __int_as_float(p.y);
        ax += wv * __uint_as_float((uint)u.x << 16);
        ay += wv * __uint_as_float((uint)u.y << 16);
        az += wv * __uint_as_float((uint)u.z << 16);
        aw += wv * __uint_as_float((uint)u.w << 16);
    }
    // reduce the 4 quarter partials (lanes l, l+16, l+32, l+48)
    ax += __shfl_xor(ax, 16); ax += __shfl_xor(ax, 32);
    ay += __shfl_xor(ay, 16); ay += __shfl_xor(ay, 32);
    az += __shfl_xor(az, 16); az += __shfl_xor(az, 32);
    aw += __shfl_xor(aw, 16); aw += __shfl_xor(aw, 32);
    if (lane < 16) {
        float4 r; r.x = ax; r.y = ay; r.z = az; r.w = aw;
        // overflow fold (normally 0 entries): exact fp32 for dropped edges
        int ovn = *ovcnt;
        if (ovn) {
            if (ovn > A_OVCAP) ovn = A_OVCAP;
            for (int i = 0; i < ovn; ++i) {
                int e = ovf[i];
                if (ei[E + e] == node) {
                    float wv = w[e];
                    float4 xv = ((const float4*)x)[(size_t)ei[e] * 16 + l];
                    r.x += wv * xv.x; r.y += wv * xv.y;
                    r.z += wv * xv.z; r.w += wv * xv.w;
                }
            }
        }
        ((float4*)out)[(size_t)node * 16 + l] = r;
    }
}

// ---------------- Path B (R4 exact pipeline, proven 200us) ----------------
#define BSH       8
#define NPB       (1 << BSH)
#define KB        ((N_NODES + NPB - 1) >> BSH)     // 391
#define FCHUNK    8192
#define SORT_CAP  4096

__global__ __launch_bounds__(256) void k_chist(
    const int* __restrict__ ei, int* __restrict__ bcur, int E) {
    __shared__ int h[KB];
    int t = threadIdx.x;
    for (int b = t; b < KB; b += 256) h[b] = 0;
    __syncthreads();
    int e0 = blockIdx.x * FCHUNK;
    #pragma unroll
    for (int k = 0; k < FCHUNK / 256; ++k) {
        int e = e0 + k * 256 + t;
        if (e < E) atomicAdd(&h[ei[E + e] >> BSH], 1);
    }
    __syncthreads();
    for (int b = t; b < KB; b += 256) if (h[b]) atomicAdd(&bcur[b], h[b]);
}

__global__ __launch_bounds__(256) void k_cscan(
    int* __restrict__ bcur, int* __restrict__ boffs) {
    __shared__ int sdata[256];
    int t = threadIdx.x;
    int i0 = 2 * t, i1 = 2 * t + 1;
    int v0 = (i0 < KB) ? bcur[i0] : 0;
    int v1 = (i1 < KB) ? bcur[i1] : 0;
    sdata[t] = v0 + v1; __syncthreads();
    for (int off = 1; off < 256; off <<= 1) {
        int v = (t >= off) ? sdata[t - off] : 0;
        __syncthreads();
        if (t >= off) sdata[t] += v;
        __syncthreads();
    }
    int run = (t == 0) ? 0 : sdata[t - 1];
    if (i0 < KB) { boffs[i0] = run; bcur[i0] = run; }
    run += v0;
    if (i1 < KB) { boffs[i1] = run; bcur[i1] = run; }
    if (t == 255) boffs[KB] = sdata[255];
}

__global__ __launch_bounds__(256) void k_cbin(
    const int* __restrict__ ei, const float* __restrict__ w,
    int* __restrict__ bcur, int2* __restrict__ stg, int E) {
    __shared__ int h[KB];
    int t = threadIdx.x;
    for (int b = t; b < KB; b += 256) h[b] = 0;
    __syncthreads();
    int e0 = blockIdx.x * FCHUNK;
    #pragma unroll
    for (int k = 0; k < FCHUNK / 256; ++k) {
        int e = e0 + k * 256 + t;
        if (e < E) atomicAdd(&h[ei[E + e] >> BSH], 1);
    }
    __syncthreads();
    for (int b = t; b < KB; b += 256) {
        int c = h[b];
        h[b] = c ? atomicAdd(&bcur[b], c) : 0;
    }
    __syncthreads();
    #pragma unroll
    for (int k = 0; k < FCHUNK / 256; ++k) {
        int e = e0 + k * 256 + t;
        if (e < E) {
            int dst = ei[E + e];
            int slot = atomicAdd(&h[dst >> BSH], 1);
            stg[slot] = make_int2(ei[e] | ((dst & (NPB - 1)) << 17),
                                  __float_as_int(w[e]));
        }
    }
}

__global__ __launch_bounds__(256) void k_csort(
    int2* __restrict__ stg, const int* __restrict__ boffs,
    int* __restrict__ offs) {
    __shared__ int2 buf[SORT_CAP];
    __shared__ int  hist[NPB];
    __shared__ int  cur[NPB];
    __shared__ int  sdata[256];
    int b = blockIdx.x, t = threadIdx.x;
    int bg = boffs[b], end = boffs[b + 1], cnt = end - bg;
    for (int n = t; n < NPB; n += 256) hist[n] = 0;
    __syncthreads();
    int nlds = cnt < SORT_CAP ? cnt : SORT_CAP;
    for (int i = t; i < nlds; i += 256) {
        int2 p = stg[bg + i];
        buf[i] = p;
        atomicAdd(&hist[(p.x >> 17) & (NPB - 1)], 1);
    }
    int2 r0{0,0}, r1{0,0}; int nr = 0;
    {
        int i0 = nlds + t, i1 = nlds + 256 + t;
        if (i0 < cnt) { r0 = stg[bg + i0]; atomicAdd(&hist[(r0.x >> 17) & (NPB - 1)], 1); nr = 1; }
        if (i1 < cnt) { r1 = stg[bg + i1]; atomicAdd(&hist[(r1.x >> 17) & (NPB - 1)], 1); nr = 2; }
    }
    __syncthreads();
    int c = hist[t];
    sdata[t] = c; __syncthreads();
    for (int off = 1; off < 256; off <<= 1) {
        int v = (t >= off) ? sdata[t - off] : 0;
        __syncthreads();
        if (t >= off) sdata[t] += v;
        __syncthreads();
    }
    int excl = (t == 0) ? 0 : sdata[t - 1];
    cur[t] = excl;
    int node = (b << BSH) + t;
    if (node < N_NODES) offs[node] = bg + excl;
    if (b == KB - 1 && t == 255) offs[N_NODES] = end;
    __syncthreads();
    for (int i = t; i < nlds; i += 256) {
        int2 p = buf[i];
        int pos = atomicAdd(&cur[(p.x >> 17) & (NPB - 1)], 1);
        stg[bg + pos] = p;
    }
    if (nr >= 1) { int pos = atomicAdd(&cur[(r0.x >> 17) & (NPB - 1)], 1); stg[bg + pos] = r0; }
    if (nr >= 2) { int pos = atomicAdd(&cur[(r1.x >> 17) & (NPB - 1)], 1); stg[bg + pos] = r1; }
}

__global__ __launch_bounds__(256) void k_gather(
    const float* __restrict__ x, const int* __restrict__ offs,
    const int2* __restrict__ stg, float* __restrict__ out) {
    int node = blockIdx.x * 4 + (threadIdx.x >> 6);
    int lane = threadIdx.x & 63;
    if (node >= N_NODES) return;
    int bg = offs[node], end = offs[node + 1];
    float a0 = 0.f, a1 = 0.f, a2 = 0.f, a3 = 0.f;
    int j = bg;
    for (; j + 3 < end; j += 4) {
        int2 p0 = stg[j];
        int2 p1 = stg[j + 1];
        int2 p2 = stg[j + 2];
        int2 p3 = stg[j + 3];
        a0 += __int_as_float(p0.y) * x[(size_t)(p0.x & 0x1FFFF) * N_FEAT + lane];
        a1 += __int_as_float(p1.y) * x[(size_t)(p1.x & 0x1FFFF) * N_FEAT + lane];
        a2 += __int_as_float(p2.y) * x[(size_t)(p2.x & 0x1FFFF) * N_FEAT + lane];
        a3 += __int_as_float(p3.y) * x[(size_t)(p3.x & 0x1FFFF) * N_FEAT + lane];
    }
    for (; j < end; ++j) {
        int2 p = stg[j];
        a0 += __int_as_float(p.y) * x[(size_t)(p.x & 0x1FFFF) * N_FEAT + lane];
    }
    out[(size_t)node * N_FEAT + lane] = (a0 + a1) + (a2 + a3);
}

// ---------------- Path C (R1 scatter) ----------------
__global__ __launch_bounds__(256) void gnn_scatter_kernel(
    const float* __restrict__ x, const int* __restrict__ ei,
    const float* __restrict__ w, float* __restrict__ out, int E) {
    int e = blockIdx.x * 4 + (threadIdx.x >> 6);
    int lane = threadIdx.x & 63;
    if (e >= E) return;
    float v = w[e] * x[(size_t)ei[e] * N_FEAT + lane];
    atomicAdd(&out[(size_t)ei[E + e] * N_FEAT + lane], v);
}

static inline size_t align16(size_t v) { return (v + 15) & ~(size_t)15; }

extern "C" void kernel_launch(void* const* d_in, const int* in_sizes, int n_in,
                              void* d_out, int out_size, void* d_ws, size_t ws_size,
                              hipStream_t stream) {
    const float* x   = (const float*)d_in[0];
    const int*   ei  = (const int*)d_in[1];
    const float* w   = (const float*)d_in[2];
    float*       out = (float*)d_out;
    const int E = in_sizes[2];
    char* ws = (char*)d_ws;

    // ---- Path A layout ----
    size_t a_xb   = 0;
    size_t a_stg  = align16(a_xb + (size_t)N_NODES * N_FEAT * 2);
    size_t a_dcnt = align16(a_stg + (size_t)N_NODES * A_DCAP * 8);
    size_t a_ovf  = align16(a_dcnt + (size_t)(N_NODES + 1) * 4);  // dcnt + ovcnt
    size_t need_a = a_ovf + (size_t)A_OVCAP * 4;

    if (ws_size >= need_a && E == 1250000) {
        ushort* xb    = (ushort*)(ws + a_xb);
        int2*   stg   = (int2*)(ws + a_stg);
        int*    dcnt  = (int*)(ws + a_dcnt);
        int*    ovcnt = dcnt + N_NODES;
        int*    ovf   = (int*)(ws + a_ovf);

        hipMemsetAsync(dcnt, 0, (size_t)(N_NODES + 1) * 4, stream);
        k_castbin<<<NBIN + NCAST, 1024, 0, stream>>>(
            x, xb, ei, w, dcnt, stg, ovf, ovcnt, E);
        k_ngather<<<(N_NODES + 3) / 4, 256, 0, stream>>>(
            xb, dcnt, stg, out, x, ei, w, ovf, ovcnt, E);
        return;
    }

    // ---- Path B layout (R4) ----
    size_t b_bcur  = 0;
    size_t b_boffs = align16(b_bcur + (size_t)KB * 4);
    size_t b_offs  = align16(b_boffs + (size_t)(KB + 1) * 4);
    size_t b_stg   = align16(b_offs + (size_t)(N_NODES + 1) * 4);
    size_t need_b  = b_stg + (size_t)E * 8;

    if (ws_size >= need_b) {
        int*  bcur  = (int*)(ws + b_bcur);
        int*  boffs = (int*)(ws + b_boffs);
        int*  offs  = (int*)(ws + b_offs);
        int2* stg   = (int2*)(ws + b_stg);
        const int nblk = (E + FCHUNK - 1) / FCHUNK;
        hipMemsetAsync(bcur, 0, (size_t)KB * 4, stream);
        k_chist<<<nblk, 256, 0, stream>>>(ei, bcur, E);
        k_cscan<<<1, 256, 0, stream>>>(bcur, boffs);
        k_cbin<<<nblk, 256, 0, stream>>>(ei, w, bcur, stg, E);
        k_csort<<<KB, 256, 0, stream>>>(stg, boffs, offs);
        k_gather<<<(N_NODES + 3) / 4, 256, 0, stream>>>(x, offs, stg, out);
        return;
    }

    // ---- Path C ----
    hipMemsetAsync(d_out, 0, (size_t)out_size * sizeof(float), stream);
    gnn_scatter_kernel<<<(E + 3) / 4, 256, 0, stream>>>(x, ei, w, out, E);
}

// Round 3
// 128.390 us; speedup vs baseline: 1.6158x; 1.6158x over previous
//
#include <hip/hip_runtime.h>
#include <hip/hip_bf16.h>

// LightGCNConv: out[dst] = sum_e w[e] * x[src_e], N=100000, d=64, E=1250000.
//
// R1: 80M fp32 device atomics -> 275us kernel (atomics at fabric, WRITE=320MB).
// R2: exact CSR; fill 8x write amp 90us + gather 88us -> 295 total.
// R3: per-bucket LDS-accumulate gather, 1563 blocks -> 471us. REVERTED.
// R4: L2-resident CSR build + reg-accumulate gather -> 200 total.
// R5: bf16 x + fixed-cap buckets (no hist/scan) -> 158.7. Harness poison of
//     256MiB d_ws + input restore = ~65us fixed overhead inside dur_us.
// R6: cast+bin fusion, 4-node/wave gather -> 158.4 (neutral).
// R7: fused per-bucket LDS sort+gather, 1024 thr -> 136.4.
// R8: 512-thr sortgather (full residency), shfl scan, ovf folded -> 131.4.
// R9: per-NODE binning (1.25M global atomic+return, scattered 8B writes over
//     51MB) -> castbin 93us alone, 207 total. Atomic latency chain through
//     coherence fabric + 64B write-allocate amp. REVERTED.
// R10: R8 structure + rank-at-count-time: keep the hist atomicAdd's return
//     as the edge's rank. sortgather: place = start[n]+rank, deleting the
//     buf[] staging + cur[] atomic pass (LDS 33.5K->17K). castbin: hb[] holds
//     bucket base; place = hb[b]+rank, deleting the 2nd LDS-atomic pass.
//     Fallback chain: A -> B (R4 exact, proven) -> C (R1).

#define N_NODES   100000
#define N_FEAT    64

// ---------------- Path A ----------------
#define A_BSH     7
#define A_NPB     (1 << A_BSH)                       // 128 nodes/bucket
#define A_KB      ((N_NODES + A_NPB - 1) >> A_BSH)   // 782 buckets
#define A_CAP     2048                               // slots/bucket (mean 1598)
#define A_FCHUNK  4096                               // edges per bin block
#define A_OVCAP   65536
#define NBIN      ((1250000 + A_FCHUNK - 1) / A_FCHUNK)   // 306 (E known)
#define NCAST     391   // 391*1024*4 float4 = 1.6016M >= 1.6M

// fused: blocks [0,NBIN) bin edges; blocks [NBIN,NBIN+NCAST) cast x->bf16
__global__ __launch_bounds__(1024) void k_castbin(
    const float* __restrict__ x, ushort* __restrict__ xb,
    const int* __restrict__ ei, const float* __restrict__ w,
    int* __restrict__ bcur, int2* __restrict__ stg,
    int* __restrict__ ovf, int* __restrict__ ovcnt, int E) {
    int t = threadIdx.x;
    if (blockIdx.x >= NBIN) {
        // ---- cast role ----
        int cb = blockIdx.x - NBIN;
        #pragma unroll
        for (int k = 0; k < 4; ++k) {
            int i4 = cb * 4096 + k * 1024 + t;           // float4 index
            if (i4 < N_NODES * N_FEAT / 4) {
                float4 v = ((const float4*)x)[i4];
                uint4 u = *(uint4*)&v;
                ushort4 r;
                r.x = (ushort)((u.x + 0x7FFFu + ((u.x >> 16) & 1)) >> 16);
                r.y = (ushort)((u.y + 0x7FFFu + ((u.y >> 16) & 1)) >> 16);
                r.z = (ushort)((u.z + 0x7FFFu + ((u.z >> 16) & 1)) >> 16);
                r.w = (ushort)((u.w + 0x7FFFu + ((u.w >> 16) & 1)) >> 16);
                ((ushort4*)xb)[i4] = r;
            }
        }
        return;
    }
    // ---- bin role: rank captured at count time; single LDS-atomic pass ----
    __shared__ int h[A_KB];      // per-bucket count (this block)
    __shared__ int hb[A_KB];     // per-bucket global base
    for (int b = t; b < A_KB; b += 1024) h[b] = 0;
    __syncthreads();
    int e0 = blockIdx.x * A_FCHUNK;
    int dstv[A_FCHUNK / 1024];
    int srcv[A_FCHUNK / 1024];
    float wv[A_FCHUNK / 1024];
    int rk[A_FCHUNK / 1024];
    #pragma unroll
    for (int k = 0; k < A_FCHUNK / 1024; ++k) {
        int e = e0 + k * 1024 + t;
        bool ok = (e < E);
        dstv[k] = ok ? ei[E + e] : -1;
        srcv[k] = ok ? ei[e] : 0;
        wv[k]   = ok ? w[e] : 0.f;
        rk[k]   = ok ? atomicAdd(&h[dstv[k] >> A_BSH], 1) : -1;
    }
    __syncthreads();
    for (int b = t; b < A_KB; b += 1024) {
        int c = h[b];
        hb[b] = c ? atomicAdd(&bcur[b], c) : 0;   // bucket-local base
    }
    __syncthreads();
    #pragma unroll
    for (int k = 0; k < A_FCHUNK / 1024; ++k) {
        if (dstv[k] >= 0) {
            int b = dstv[k] >> A_BSH;
            int loc = hb[b] + rk[k];
            if (loc < A_CAP) {
                stg[b * A_CAP + loc] =
                    make_int2(srcv[k] | ((dstv[k] & (A_NPB - 1)) << 17),
                              __float_as_int(wv[k]));
            } else {
                int oi = atomicAdd(ovcnt, 1);
                if (oi < A_OVCAP) ovf[oi] = e0 + k * 1024 + t;
            }
        }
    }
}

// fused per-bucket counting sort (rank-based, single LDS-atomic pass) +
// quarter-wave gather. 512 threads, ~17KB LDS -> 4 blk/CU wave-capped,
// whole grid resident. Overflow fix-up folded (normally ovcnt == 0).
__global__ __launch_bounds__(512, 8) void k_sortgather(
    const ushort* __restrict__ xb, const int* __restrict__ bcur,
    const int2* __restrict__ stg, float* __restrict__ out,
    const float* __restrict__ x, const int* __restrict__ ei,
    const float* __restrict__ w, const int* __restrict__ ovf,
    const int* __restrict__ ovcnt, int E) {
    __shared__ int2 srt[A_CAP];      // 16 KB sorted payload
    __shared__ int  hist[A_NPB];     // per-node counts
    __shared__ int  start[A_NPB];    // per-node exclusive offsets
    __shared__ int  ovn;
    int b = blockIdx.x, t = threadIdx.x;
    int cnt = bcur[b];
    if (cnt > A_CAP) cnt = A_CAP;
    int base = b * A_CAP;

    if (t < A_NPB) hist[t] = 0;
    if (t == 0) { int n = *ovcnt; ovn = (n > A_OVCAP) ? A_OVCAP : n; }
    __syncthreads();
    // count + capture rank (A_CAP == 4*512: statically-indexed registers)
    int2 pv[4]; int nn[4]; int rk[4];
    #pragma unroll
    for (int k = 0; k < 4; ++k) {
        int i = k * 512 + t;
        bool ok = (i < cnt);
        int2 p = ok ? stg[base + i] : make_int2(0, 0);
        pv[k] = p;
        nn[k] = (p.x >> 17) & (A_NPB - 1);
        rk[k] = ok ? atomicAdd(&hist[nn[k]], 1) : -1;
    }
    __syncthreads();
    // single-wave exclusive scan of the 128 counts (wave 0, 2 entries/lane)
    if (t < 64) {
        int s0 = hist[2 * t], s1 = hist[2 * t + 1];
        int ps = s0 + s1;
        #pragma unroll
        for (int off = 1; off < 64; off <<= 1) {
            int v = __shfl_up(ps, off);
            if (t >= off) ps += v;
        }
        int excl = ps - (s0 + s1);
        start[2 * t]     = excl;
        start[2 * t + 1] = excl + s0;
    }
    __syncthreads();
    // place directly: pos = start[node] + rank (no atomics, no staging)
    #pragma unroll
    for (int k = 0; k < 4; ++k) {
        if (rk[k] >= 0) srt[start[nn[k]] + rk[k]] = pv[k];
    }
    __syncthreads();

    // gather: 8 waves x 4 quarter-slots = 32 nodes per pass, 4 passes
    int wid  = t >> 6;                 // 0..7
    int lane = t & 63;
    int q    = lane >> 4;              // quarter slot
    int l    = lane & 15;              // ushort4 column
    const ushort4* xb4 = (const ushort4*)xb;
    int novf = ovn;
    #pragma unroll
    for (int pass = 0; pass < 4; ++pass) {
        int n = pass * 32 + wid * 4 + q;           // local node 0..127
        int node = (b << A_BSH) + n;
        int j = start[n], end = start[n] + hist[n];
        float ax0 = 0.f, ay0 = 0.f, az0 = 0.f, aw0 = 0.f;
        float ax1 = 0.f, ay1 = 0.f, az1 = 0.f, aw1 = 0.f;
        for (; j + 1 < end; j += 2) {
            int2 p0 = srt[j];
            int2 p1 = srt[j + 1];
            ushort4 u0 = xb4[(size_t)(p0.x & 0x1FFFF) * 16 + l];
            ushort4 u1 = xb4[(size_t)(p1.x & 0x1FFFF) * 16 + l];
            float w0 = __int_as_float(p0.y), w1 = __int_as_float(p1.y);
            ax0 += w0 * __uint_as_float((uint)u0.x << 16);
            ay0 += w0 * __uint_as_float((uint)u0.y << 16);
            az0 += w0 * __uint_as_float((uint)u0.z << 16);
            aw0 += w0 * __uint_as_float((uint)u0.w << 16);
            ax1 += w1 * __uint_as_float((uint)u1.x << 16);
            ay1 += w1 * __uint_as_float((uint)u1.y << 16);
            az1 += w1 * __uint_as_float((uint)u1.z << 16);
            aw1 += w1 * __uint_as_float((uint)u1.w << 16);
        }
        if (j < end) {
            int2 p = srt[j];
            ushort4 u = xb4[(size_t)(p.x & 0x1FFFF) * 16 + l];
            float wv = __int_as_float(p.y);
            ax0 += wv * __uint_as_float((uint)u.x << 16);
            ay0 += wv * __uint_as_float((uint)u.y << 16);
            az0 += wv * __uint_as_float((uint)u.z << 16);
            aw0 += wv * __uint_as_float((uint)u.w << 16);
        }
        // overflow fold (normally novf == 0): exact fp32 for dropped edges
        if (novf) {
            for (int i = 0; i < novf; ++i) {
                int e = ovf[i];
                if (ei[E + e] == node) {
                    float wv = w[e];
                    float4 xv = ((const float4*)x)[(size_t)ei[e] * 16 + l];
                    ax0 += wv * xv.x; ay0 += wv * xv.y;
                    az0 += wv * xv.z; aw0 += wv * xv.w;
                }
            }
        }
        if (node < N_NODES) {
            float4 r;
            r.x = ax0 + ax1; r.y = ay0 + ay1;
            r.z = az0 + az1; r.w = aw0 + aw1;
            ((float4*)out)[(size_t)node * 16 + l] = r;
        }
    }
}

// ---------------- Path B (R4 exact pipeline, proven 200us) ----------------
#define BSH       8
#define NPB       (1 << BSH)
#define KB        ((N_NODES + NPB - 1) >> BSH)     // 391
#define FCHUNK    8192
#define SORT_CAP  4096

__global__ __launch_bounds__(256) void k_chist(
    const int* __restrict__ ei, int* __restrict__ bcur, int E) {
    __shared__ int h[KB];
    int t = threadIdx.x;
    for (int b = t; b < KB; b += 256) h[b] = 0;
    __syncthreads();
    int e0 = blockIdx.x * FCHUNK;
    #pragma unroll
    for (int k = 0; k < FCHUNK / 256; ++k) {
        int e = e0 + k * 256 + t;
        if (e < E) atomicAdd(&h[ei[E + e] >> BSH], 1);
    }
    __syncthreads();
    for (int b = t; b < KB; b += 256) if (h[b]) atomicAdd(&bcur[b], h[b]);
}

__global__ __launch_bounds__(256) void k_cscan(
    int* __restrict__ bcur, int* __restrict__ boffs) {
    __shared__ int sdata[256];
    int t = threadIdx.x;
    int i0 = 2 * t, i1 = 2 * t + 1;
    int v0 = (i0 < KB) ? bcur[i0] : 0;
    int v1 = (i1 < KB) ? bcur[i1] : 0;
    sdata[t] = v0 + v1; __syncthreads();
    for (int off = 1; off < 256; off <<= 1) {
        int v = (t >= off) ? sdata[t - off] : 0;
        __syncthreads();
        if (t >= off) sdata[t] += v;
        __syncthreads();
    }
    int run = (t == 0) ? 0 : sdata[t - 1];
    if (i0 < KB) { boffs[i0] = run; bcur[i0] = run; }
    run += v0;
    if (i1 < KB) { boffs[i1] = run; bcur[i1] = run; }
    if (t == 255) boffs[KB] = sdata[255];
}

__global__ __launch_bounds__(256) void k_cbin(
    const int* __restrict__ ei, const float* __restrict__ w,
    int* __restrict__ bcur, int2* __restrict__ stg, int E) {
    __shared__ int h[KB];
    int t = threadIdx.x;
    for (int b = t; b < KB; b += 256) h[b] = 0;
    __syncthreads();
    int e0 = blockIdx.x * FCHUNK;
    #pragma unroll
    for (int k = 0; k < FCHUNK / 256; ++k) {
        int e = e0 + k * 256 + t;
        if (e < E) atomicAdd(&h[ei[E + e] >> BSH], 1);
    }
    __syncthreads();
    for (int b = t; b < KB; b += 256) {
        int c = h[b];
        h[b] = c ? atomicAdd(&bcur[b], c) : 0;
    }
    __syncthreads();
    #pragma unroll
    for (int k = 0; k < FCHUNK / 256; ++k) {
        int e = e0 + k * 256 + t;
        if (e < E) {
            int dst = ei[E + e];
            int slot = atomicAdd(&h[dst >> BSH], 1);
            stg[slot] = make_int2(ei[e] | ((dst & (NPB - 1)) << 17),
                                  __float_as_int(w[e]));
        }
    }
}

__global__ __launch_bounds__(256) void k_csort(
    int2* __restrict__ stg, const int* __restrict__ boffs,
    int* __restrict__ offs) {
    __shared__ int2 buf[SORT_CAP];
    __shared__ int  hist[NPB];
    __shared__ int  cur[NPB];
    __shared__ int  sdata[256];
    int b = blockIdx.x, t = threadIdx.x;
    int bg = boffs[b], end = boffs[b + 1], cnt = end - bg;
    for (int n = t; n < NPB; n += 256) hist[n] = 0;
    __syncthreads();
    int nlds = cnt < SORT_CAP ? cnt : SORT_CAP;
    for (int i = t; i < nlds; i += 256) {
        int2 p = stg[bg + i];
        buf[i] = p;
        atomicAdd(&hist[(p.x >> 17) & (NPB - 1)], 1);
    }
    int2 r0{0,0}, r1{0,0}; int nr = 0;
    {
        int i0 = nlds + t, i1 = nlds + 256 + t;
        if (i0 < cnt) { r0 = stg[bg + i0]; atomicAdd(&hist[(r0.x >> 17) & (NPB - 1)], 1); nr = 1; }
        if (i1 < cnt) { r1 = stg[bg + i1]; atomicAdd(&hist[(r1.x >> 17) & (NPB - 1)], 1); nr = 2; }
    }
    __syncthreads();
    int c = hist[t];
    sdata[t] = c; __syncthreads();
    for (int off = 1; off < 256; off <<= 1) {
        int v = (t >= off) ? sdata[t - off] : 0;
        __syncthreads();
        if (t >= off) sdata[t] += v;
        __syncthreads();
    }
    int excl = (t == 0) ? 0 : sdata[t - 1];
    cur[t] = excl;
    int node = (b << BSH) + t;
    if (node < N_NODES) offs[node] = bg + excl;
    if (b == KB - 1 && t == 255) offs[N_NODES] = end;
    __syncthreads();
    for (int i = t; i < nlds; i += 256) {
        int2 p = buf[i];
        int pos = atomicAdd(&cur[(p.x >> 17) & (NPB - 1)], 1);
        stg[bg + pos] = p;
    }
    if (nr >= 1) { int pos = atomicAdd(&cur[(r0.x >> 17) & (NPB - 1)], 1); stg[bg + pos] = r0; }
    if (nr >= 2) { int pos = atomicAdd(&cur[(r1.x >> 17) & (NPB - 1)], 1); stg[bg + pos] = r1; }
}

__global__ __launch_bounds__(256) void k_gather(
    const float* __restrict__ x, const int* __restrict__ offs,
    const int2* __restrict__ stg, float* __restrict__ out) {
    int node = blockIdx.x * 4 + (threadIdx.x >> 6);
    int lane = threadIdx.x & 63;
    if (node >= N_NODES) return;
    int bg = offs[node], end = offs[node + 1];
    float a0 = 0.f, a1 = 0.f, a2 = 0.f, a3 = 0.f;
    int j = bg;
    for (; j + 3 < end; j += 4) {
        int2 p0 = stg[j];
        int2 p1 = stg[j + 1];
        int2 p2 = stg[j + 2];
        int2 p3 = stg[j + 3];
        a0 += __int_as_float(p0.y) * x[(size_t)(p0.x & 0x1FFFF) * N_FEAT + lane];
        a1 += __int_as_float(p1.y) * x[(size_t)(p1.x & 0x1FFFF) * N_FEAT + lane];
        a2 += __int_as_float(p2.y) * x[(size_t)(p2.x & 0x1FFFF) * N_FEAT + lane];
        a3 += __int_as_float(p3.y) * x[(size_t)(p3.x & 0x1FFFF) * N_FEAT + lane];
    }
    for (; j < end; ++j) {
        int2 p = stg[j];
        a0 += __int_as_float(p.y) * x[(size_t)(p.x & 0x1FFFF) * N_FEAT + lane];
    }
    out[(size_t)node * N_FEAT + lane] = (a0 + a1) + (a2 + a3);
}

// ---------------- Path C (R1 scatter) ----------------
__global__ __launch_bounds__(256) void gnn_scatter_kernel(
    const float* __restrict__ x, const int* __restrict__ ei,
    const float* __restrict__ w, float* __restrict__ out, int E) {
    int e = blockIdx.x * 4 + (threadIdx.x >> 6);
    int lane = threadIdx.x & 63;
    if (e >= E) return;
    float v = w[e] * x[(size_t)ei[e] * N_FEAT + lane];
    atomicAdd(&out[(size_t)ei[E + e] * N_FEAT + lane], v);
}

static inline size_t align16(size_t v) { return (v + 15) & ~(size_t)15; }

extern "C" void kernel_launch(void* const* d_in, const int* in_sizes, int n_in,
                              void* d_out, int out_size, void* d_ws, size_t ws_size,
                              hipStream_t stream) {
    const float* x   = (const float*)d_in[0];
    const int*   ei  = (const int*)d_in[1];
    const float* w   = (const float*)d_in[2];
    float*       out = (float*)d_out;
    const int E = in_sizes[2];
    char* ws = (char*)d_ws;

    // ---- Path A layout ----
    size_t a_xb   = 0;
    size_t a_stg  = align16(a_xb + (size_t)N_NODES * N_FEAT * 2);
    size_t a_bcur = align16(a_stg + (size_t)A_KB * A_CAP * 8);    // KB ints + ovcnt
    size_t a_ovf  = align16(a_bcur + (size_t)(A_KB + 1) * 4);
    size_t need_a = a_ovf + (size_t)A_OVCAP * 4;

    if (ws_size >= need_a && E == 1250000) {
        ushort* xb    = (ushort*)(ws + a_xb);
        int2*   stg   = (int2*)(ws + a_stg);
        int*    bcur  = (int*)(ws + a_bcur);
        int*    ovcnt = bcur + A_KB;
        int*    ovf   = (int*)(ws + a_ovf);

        hipMemsetAsync(bcur, 0, (size_t)(A_KB + 1) * 4, stream);
        k_castbin<<<NBIN + NCAST, 1024, 0, stream>>>(
            x, xb, ei, w, bcur, stg, ovf, ovcnt, E);
        k_sortgather<<<A_KB, 512, 0, stream>>>(
            xb, bcur, stg, out, x, ei, w, ovf, ovcnt, E);
        return;
    }

    // ---- Path B layout (R4) ----
    size_t b_bcur  = 0;
    size_t b_boffs = align16(b_bcur + (size_t)KB * 4);
    size_t b_offs  = align16(b_boffs + (size_t)(KB + 1) * 4);
    size_t b_stg   = align16(b_offs + (size_t)(N_NODES + 1) * 4);
    size_t need_b  = b_stg + (size_t)E * 8;

    if (ws_size >= need_b) {
        int*  bcur  = (int*)(ws + b_bcur);
        int*  boffs = (int*)(ws + b_boffs);
        int*  offs  = (int*)(ws + b_offs);
        int2* stg   = (int2*)(ws + b_stg);
        const int nblk = (E + FCHUNK - 1) / FCHUNK;
        hipMemsetAsync(bcur, 0, (size_t)KB * 4, stream);
        k_chist<<<nblk, 256, 0, stream>>>(ei, bcur, E);
        k_cscan<<<1, 256, 0, stream>>>(bcur, boffs);
        k_cbin<<<nblk, 256, 0, stream>>>(ei, w, bcur, stg, E);
        k_csort<<<KB, 256, 0, stream>>>(stg, boffs, offs);
        k_gather<<<(N_NODES + 3) / 4, 256, 0, stream>>>(x, offs, stg, out);
        return;
    }

    // ---- Path C ----
    hipMemsetAsync(d_out, 0, (size_t)out_size * sizeof(float), stream);
    gnn_scatter_kernel<<<(E + 3) / 4, 256, 0, stream>>>(x, ei, w, out, E);
}